// Round 1
// baseline (407.257 us; speedup 1.0000x reference)
//
#include <hip/hip_runtime.h>
#include <stdint.h>

// Problem constants (from reference): B=4, S=4096, D=2, 3 RK2 steps.
#define BATCH   4
#define SEQ     4096
#define WPR     64                  // 64-bit bitmask words per row (SEQ/64)
#define NROWS   (BATCH * SEQ)       // 16384
#define DTS     0.1f
#define HALF_DT 0.05f
#define EPS     1e-8f

// ---------------------------------------------------------------------------
// Pass 1: compress the fp32 0/1 mask (268 MB) into a bitmask (8 MB) in ws.
// One thread per output 64-bit word: 16x float4 loads (256 B/thread).
// This is the single unavoidable full read of the mask.
// ---------------------------------------------------------------------------
__global__ void compress_mask(const float* __restrict__ mask,
                              unsigned long long* __restrict__ bits) {
    int w = blockIdx.x * blockDim.x + threadIdx.x;      // word id, NROWS*WPR total
    const float4* src = reinterpret_cast<const float4*>(mask) + (size_t)w * 16;
    unsigned long long acc = 0ull;
#pragma unroll
    for (int it = 0; it < 16; ++it) {
        float4 v = src[it];
        unsigned long long n =
              (unsigned long long)(v.x != 0.f)
            | ((unsigned long long)(v.y != 0.f) << 1)
            | ((unsigned long long)(v.z != 0.f) << 2)
            | ((unsigned long long)(v.w != 0.f) << 3);
        acc |= n << (it * 4);
    }
    bits[w] = acc;
}

// ---------------------------------------------------------------------------
// Force + RK2-stage update. Wave-per-row: lane l owns bitmask word l of the
// row (coalesced 512 B/wave), iterates set bits with ctz, gathers float2
// state (32 KB/batch, L1-resident), then a 64-lane xor-butterfly reduction.
// PHASE 0: k1 = M@p - p; psi_star = renorm(p + DT*k1, r);  writes k1,star,r.
// PHASE 1: k2 = M@star - star; p_new = renorm(p + DT/2*(k1+k2), r) -> outbuf.
// ---------------------------------------------------------------------------
template <int PHASE>
__global__ void force_step(const unsigned long long* __restrict__ bits,
                           const float2* __restrict__ pIn,     // current state
                           const float2* __restrict__ gsrc,    // gather source (p or star)
                           float2* __restrict__ k1buf,
                           float2* __restrict__ starbuf,
                           float*  __restrict__ rbuf,
                           float2* __restrict__ outbuf) {
    const int wave = threadIdx.x >> 6;
    const int lane = threadIdx.x & 63;
    const int row  = blockIdx.x * (blockDim.x >> 6) + wave;   // 0..NROWS
    const int b    = row >> 12;                                // row / SEQ
    const float2* gb = gsrc + ((size_t)b << 12);               // batch base

    unsigned long long w = bits[(size_t)row * WPR + lane];
    float sx = 0.f, sy = 0.f;
    const int base = lane << 6;
    while (w) {
        int j = __builtin_ctzll(w);
        w &= (w - 1);
        float2 v = gb[base + j];
        sx += v.x; sy += v.y;
    }
#pragma unroll
    for (int m = 32; m >= 1; m >>= 1) {
        sx += __shfl_xor(sx, m, 64);
        sy += __shfl_xor(sy, m, 64);
    }
    if (lane == 0) {
        if (PHASE == 0) {
            float2 p = pIn[row];
            float r   = sqrtf(p.x * p.x + p.y * p.y);
            float k1x = sx - p.x, k1y = sy - p.y;
            float tx  = p.x + DTS * k1x, ty = p.y + DTS * k1y;
            float sc  = r / (sqrtf(tx * tx + ty * ty) + EPS);
            k1buf[row]   = make_float2(k1x, k1y);
            starbuf[row] = make_float2(tx * sc, ty * sc);
            rbuf[row]    = r;
        } else {
            float2 st = gsrc[row];                 // psi_star (self)
            float k2x = sx - st.x, k2y = sy - st.y;
            float2 p  = pIn[row];
            float2 k1 = k1buf[row];
            float nx  = p.x + HALF_DT * (k1.x + k2x);
            float ny  = p.y + HALF_DT * (k1.y + k2y);
            float sc  = rbuf[row] / (sqrtf(nx * nx + ny * ny) + EPS);
            outbuf[row] = make_float2(nx * sc, ny * sc);
        }
    }
}

extern "C" void kernel_launch(void* const* d_in, const int* in_sizes, int n_in,
                              void* d_out, int out_size, void* d_ws, size_t ws_size,
                              hipStream_t stream) {
    const float* psi  = (const float*)d_in[0];   // [4,4096,2] fp32
    const float* mask = (const float*)d_in[1];   // [4,4096,4096] fp32 (0/1)
    float2* out2 = (float2*)d_out;               // [4,4096,2] fp32

    // Workspace layout: bitmask 8 MB | p 128 KB | k1 128 KB | star 128 KB | r 64 KB
    char* ws = (char*)d_ws;
    unsigned long long* bits = (unsigned long long*)ws;
    float2* p    = (float2*)(ws + (size_t)NROWS * WPR * 8);
    float2* k1   = p + NROWS;
    float2* star = k1 + NROWS;
    float*  rbuf = (float*)(star + NROWS);

    // 1M words / 256 threads = 4096 blocks (exact)
    compress_mask<<<NROWS * WPR / 256, 256, 0, stream>>>(mask, bits);

    const float2* psi2 = (const float2*)psi;
    const int fgrid = NROWS / 4;                 // 4 waves (rows) per 256-thr block

    // step 1 (reads psi from d_in, writes p into ws)
    force_step<0><<<fgrid, 256, 0, stream>>>(bits, psi2, psi2, k1, star, rbuf, nullptr);
    force_step<1><<<fgrid, 256, 0, stream>>>(bits, psi2, star, k1, star, rbuf, p);
    // step 2 (in-place p update; PHASE 1 only reads its own p[row])
    force_step<0><<<fgrid, 256, 0, stream>>>(bits, p, p, k1, star, rbuf, nullptr);
    force_step<1><<<fgrid, 256, 0, stream>>>(bits, p, star, k1, star, rbuf, p);
    // step 3 (writes final state straight to d_out)
    force_step<0><<<fgrid, 256, 0, stream>>>(bits, p, p, k1, star, rbuf, nullptr);
    force_step<1><<<fgrid, 256, 0, stream>>>(bits, p, star, k1, star, rbuf, out2);
}